// Round 6
// baseline (1226.029 us; speedup 1.0000x reference)
//
#include <hip/hip_runtime.h>
#include <hip/hip_bf16.h>
#include <stdint.h>

#define B_DIM 16384
#define D_DIM 512
// Embeddings quantized as fp8(8*x): dot scales by 64. logit = dot/64/T.
#define LOGIT_SCALE (1.0f / (0.07f * 64.0f))

typedef int i32x4 __attribute__((ext_vector_type(4)));
typedef int i32x8 __attribute__((ext_vector_type(8)));
typedef float f32x16 __attribute__((ext_vector_type(16)));

typedef const __attribute__((address_space(1))) void* gptr_t;
typedef __attribute__((address_space(3))) void* lptr_t;

// Swizzled global fp8 layout (identical for Pn and Tn), designed so that
// (a) GEMM staging of a 16-KB (128-row... actually 256rowx64k) half is a pure
//     linear copy, and (b) the 32x32x64 fragment read is lane-linear in LDS.
// addr(row,k) = ((row>>8)*4 + (k>>7))*32768        // (row-block 256, k-tile 128)
//             + ((k>>6)&1)*16384                   // kh half (64 k-bytes)
//             + ((row>>5)&7)*2048                  // rb: 32-row block
//             + ((k>>4)&1)*1024                    // 16-B half of the 32-B k-block
//             + (((k>>5)&1)*32 + (row&31))*16      // q = kb*32 + row5  (== lane)
//             + (k&15)

// One wave per row: load 512 fp32, L2-normalize, scale by 8, quantize to
// fp8 e4m3, store into the swizzled layout (64 scattered 8-B stores/row).
__global__ __launch_bounds__(256) void normalize_kernel(const float* __restrict__ in,
                                                        uint8_t* __restrict__ out) {
  int wid = threadIdx.x >> 6;
  int lane = threadIdx.x & 63;
  int row = blockIdx.x * 4 + wid;
  const float* r = in + (size_t)row * D_DIM;
  float4 v0 = ((const float4*)r)[lane * 2];
  float4 v1 = ((const float4*)r)[lane * 2 + 1];
  float ssq = v0.x * v0.x + v0.y * v0.y + v0.z * v0.z + v0.w * v0.w +
              v1.x * v1.x + v1.y * v1.y + v1.z * v1.z + v1.w * v1.w;
#pragma unroll
  for (int m = 1; m < 64; m <<= 1) ssq += __shfl_xor(ssq, m);
  float s8 = 8.0f / fmaxf(sqrtf(ssq), 1e-12f);
  int w0 = __builtin_amdgcn_cvt_pk_fp8_f32(v0.x * s8, v0.y * s8, 0, false);
  w0 = __builtin_amdgcn_cvt_pk_fp8_f32(v0.z * s8, v0.w * s8, w0, true);
  int w1 = __builtin_amdgcn_cvt_pk_fp8_f32(v1.x * s8, v1.y * s8, 0, false);
  w1 = __builtin_amdgcn_cvt_pk_fp8_f32(v1.z * s8, v1.w * s8, w1, true);
  int kt = lane >> 4, kh = (lane >> 3) & 1, kb = (lane >> 2) & 1;
  int half = (lane >> 1) & 1, bo = (lane & 1) * 8;
  size_t addr = ((size_t)(row >> 8) * 4 + kt) * 32768 + (size_t)kh * 16384 +
                ((row >> 5) & 7) * 2048 + half * 1024 +
                (((kb << 5) | (row & 31)) * 16) + bo;
  uint2 o;
  o.x = (unsigned)w0;
  o.y = (unsigned)w1;
  *(uint2*)(out + addr) = o;
}

// 256x256-tile NT GEMM in MX-fp8 (unity scales). 8 waves (2Mx4N), BK=128
// split into two kh-halves of 64; 4-phase/K-tile schedule with the verified
// round-3 stage/wait ledger; lane-linear LDS (zero bank conflicts).
// Fused exp + row/col sums + diag.
__global__ __launch_bounds__(512, 2) void infonce_main(const uint8_t* __restrict__ P,
                                                       const uint8_t* __restrict__ T,
                                                       float* __restrict__ row_sum,
                                                       float* __restrict__ col_sum,
                                                       float* __restrict__ diag) {
  __shared__ __align__(16) uint8_t As[2][2][16384];  // [dbuf][kh][16 KB]
  __shared__ __align__(16) uint8_t Bs[2][2][16384];

  int bid = blockIdx.x;  // 4096 blocks; round-2..4 raster (74 MB FETCH proven)
  int xcd = bid & 7;
  int q = bid >> 3;
  int brow = (xcd * 8 + (q & 7)) << 8;
  int bcol = (q >> 3) << 8;

  int tid = threadIdx.x;
  int lane = tid & 63;
  int wid = tid >> 6;
  int wr = (wid >> 2) * 128;  // 2 M-wave groups
  int wc = (wid & 3) * 64;    // 4 N-waves
  int l31 = lane & 31, l5 = lane >> 5;

  f32x16 acc[4][2] = {};

  // Stage one 16-KB half (256 rows x 64 k-bytes): pure linear copy.
#define STAGE_HALF(ARR, SRC, RB, BUF, KH, KT)                                  \
  do {                                                                         \
    size_t base_ = ((size_t)((RB) >> 8) * 4 + (KT)) * 32768 + (KH) * 16384;    \
    _Pragma("unroll") for (int it = 0; it < 2; ++it) {                         \
      int s_ = it * 512 + tid;                                                 \
      __builtin_amdgcn_global_load_lds((gptr_t)(SRC + base_ + (size_t)s_ * 16),\
                                       (lptr_t)(&ARR[BUF][KH][0] + s_ * 16),   \
                                       16, 0, 0);                              \
    }                                                                          \
  } while (0)

  // Lane-linear fragment reads (2 x ds_read_b128 per 32x32 tile).
#define RD_A(dst, BUF, KH, MH)                                                 \
  _Pragma("unroll") for (int m2 = 0; m2 < 2; ++m2) {                           \
    const uint8_t* p_ =                                                        \
        &As[BUF][KH][(((wid >> 2) * 4 + (MH)*2 + m2) * 2048) + lane * 16];     \
    i32x4 lo_ = *(const i32x4*)p_;                                             \
    i32x4 hi_ = *(const i32x4*)(p_ + 1024);                                    \
    dst[m2] = __builtin_shufflevector(lo_, hi_, 0, 1, 2, 3, 4, 5, 6, 7);       \
  }

#define RD_B(dst, BUF, KH)                                                     \
  _Pragma("unroll") for (int n2 = 0; n2 < 2; ++n2) {                           \
    const uint8_t* p_ =                                                        \
        &Bs[BUF][KH][(((wid & 3) * 2 + n2) * 2048) + lane * 16];               \
    i32x4 lo_ = *(const i32x4*)p_;                                             \
    i32x4 hi_ = *(const i32x4*)(p_ + 1024);                                    \
    dst[n2] = __builtin_shufflevector(lo_, hi_, 0, 1, 2, 3, 4, 5, 6, 7);       \
  }

#define MM(MH, aa, bb)                                                         \
  _Pragma("unroll") for (int m2 = 0; m2 < 2; ++m2)                             \
      _Pragma("unroll") for (int n2 = 0; n2 < 2; ++n2)                         \
          acc[(MH)*2 + m2][n2] =                                               \
      __builtin_amdgcn_mfma_scale_f32_32x32x64_f8f6f4(                         \
          aa[m2], bb[n2], acc[(MH)*2 + m2][n2], 0, 0, 0, 0x7F7F7F7F, 0,        \
          0x7F7F7F7F)

#define PHASE(KH, MH, READB, STAGE_STMT, VMCNT_STMT)                           \
  do {                                                                         \
    i32x8 a_[2];                                                               \
    RD_A(a_, cur, KH, MH);                                                     \
    if (READB) { RD_B(b_, cur, KH); }                                          \
    STAGE_STMT;                                                                \
    VMCNT_STMT;                                                                \
    __builtin_amdgcn_s_barrier();                                              \
    __builtin_amdgcn_s_setprio(1);                                             \
    MM(MH, a_, b_);                                                            \
    __builtin_amdgcn_s_setprio(0);                                             \
    __builtin_amdgcn_s_barrier();                                              \
  } while (0)

  // Prologue: Ak0(0),Bk0(0),Ak1(0),Bk1(0),Ak0(1),Bk0(1); confirm first two.
  STAGE_HALF(As, P, brow, 0, 0, 0);
  STAGE_HALF(Bs, T, bcol, 0, 0, 0);
  STAGE_HALF(As, P, brow, 0, 1, 0);
  STAGE_HALF(Bs, T, bcol, 0, 1, 0);
  STAGE_HALF(As, P, brow, 1, 0, 1);
  STAGE_HALF(Bs, T, bcol, 1, 0, 1);
  asm volatile("s_waitcnt vmcnt(8)" ::: "memory");
  __builtin_amdgcn_s_barrier();

#pragma unroll
  for (int t = 0; t < 4; ++t) {
    const int cur = t & 1, nb = (t + 1) & 1;
    i32x8 b_[2];
    // Ledger (verified for NT=4): issue Ak1(t+1)@p1, Bk1(t+1)@p2,
    // Ak0(t+2)@p3, Bk0(t+2)@p4; vmcnt(6)@p2/p4 (tail: p2 t==3 -> 0,
    // p4 t==2 -> 4). Every half is vmcnt-confirmed + barriered strictly
    // before its first ds_read.
    PHASE(0, 0, 1, { if (t < 3) STAGE_HALF(As, P, brow, nb, 1, t + 1); }, {});
    PHASE(0, 1, 0, { if (t < 3) STAGE_HALF(Bs, T, bcol, nb, 1, t + 1); },
          {
            if (t < 3) asm volatile("s_waitcnt vmcnt(6)" ::: "memory");
            else       asm volatile("s_waitcnt vmcnt(0)" ::: "memory");
          });
    PHASE(1, 0, 1, { if (t < 2) STAGE_HALF(As, P, brow, cur, 0, t + 2); }, {});
    PHASE(1, 1, 0, { if (t < 2) STAGE_HALF(Bs, T, bcol, cur, 0, t + 2); },
          {
            if (t < 2)       asm volatile("s_waitcnt vmcnt(6)" ::: "memory");
            else if (t == 2) asm volatile("s_waitcnt vmcnt(4)" ::: "memory");
          });
  }
#undef PHASE
#undef MM
#undef RD_A
#undef RD_B
#undef STAGE_HALF

  // Epilogue. 32x32 C/D map (m74/m101): row=(j&3)+8*(j>>2)+4*(lane>>5),
  // col=lane&31. logit = acc * INV_T/64; capture diag; exp in place.
#pragma unroll
  for (int mt = 0; mt < 4; ++mt)
#pragma unroll
    for (int nt = 0; nt < 2; ++nt)
#pragma unroll
      for (int j = 0; j < 16; ++j) {
        float logit = acc[mt][nt][j] * LOGIT_SCALE;
        int grow = brow + wr + mt * 32 + (j & 3) + 8 * (j >> 2) + 4 * l5;
        int gcol = bcol + wc + nt * 32 + l31;
        if (grow == gcol) diag[grow] = logit;
        acc[mt][nt][j] = __expf(logit);
      }

  // Row sums: sum the 2 n-tiles, then reduce the 32-lane col group.
#pragma unroll
  for (int mt = 0; mt < 4; ++mt)
#pragma unroll
    for (int j = 0; j < 16; ++j) {
      float rs = acc[mt][0][j] + acc[mt][1][j];
      rs += __shfl_xor(rs, 1);
      rs += __shfl_xor(rs, 2);
      rs += __shfl_xor(rs, 4);
      rs += __shfl_xor(rs, 8);
      rs += __shfl_xor(rs, 16);
      if (l31 == 0)
        atomicAdd(&row_sum[brow + wr + mt * 32 + (j & 3) + 8 * (j >> 2) + 4 * l5], rs);
    }

  // Col sums: sum regs (16 rows) + the two lane-half row groups.
#pragma unroll
  for (int nt = 0; nt < 2; ++nt) {
    float cs = 0.f;
#pragma unroll
    for (int mt = 0; mt < 4; ++mt)
#pragma unroll
      for (int j = 0; j < 16; ++j) cs += acc[mt][nt][j];
    cs += __shfl_xor(cs, 32);
    if (l5 == 0) atomicAdd(&col_sum[bcol + wc + nt * 32 + l31], cs);
  }
}

__global__ __launch_bounds__(256) void finalize_kernel(const float* __restrict__ rs,
                                                       const float* __restrict__ cs,
                                                       const float* __restrict__ dg,
                                                       float* __restrict__ out) {
  float s = 0.f;
  for (int i = threadIdx.x; i < B_DIM; i += 256)
    s += 0.5f * (logf(rs[i]) + logf(cs[i])) - dg[i];
#pragma unroll
  for (int m = 1; m < 64; m <<= 1) s += __shfl_xor(s, m);
  __shared__ float red[4];
  if ((threadIdx.x & 63) == 0) red[threadIdx.x >> 6] = s;
  __syncthreads();
  if (threadIdx.x == 0)
    out[0] = (red[0] + red[1] + red[2] + red[3]) * (1.0f / (float)B_DIM);
}

extern "C" void kernel_launch(void* const* d_in, const int* in_sizes, int n_in,
                              void* d_out, int out_size, void* d_ws, size_t ws_size,
                              hipStream_t stream) {
  const float* p = (const float*)d_in[0];
  const float* t = (const float*)d_in[1];
  float* out = (float*)d_out;

  char* ws = (char*)d_ws;
  const size_t embBytes = (size_t)B_DIM * D_DIM;  // 8 MB fp8
  uint8_t* Pn = (uint8_t*)ws;
  uint8_t* Tn = (uint8_t*)(ws + embBytes);
  float* row_sum = (float*)(ws + 2 * embBytes);
  float* col_sum = row_sum + B_DIM;
  float* diag = col_sum + B_DIM;

  hipMemsetAsync(row_sum, 0, 2 * (size_t)B_DIM * sizeof(float), stream);
  normalize_kernel<<<B_DIM / 4, 256, 0, stream>>>(p, Pn);
  normalize_kernel<<<B_DIM / 4, 256, 0, stream>>>(t, Tn);
  infonce_main<<<(B_DIM / 256) * (B_DIM / 256), 512, 0, stream>>>(Pn, Tn, row_sum, col_sum, diag);
  finalize_kernel<<<1, 256, 0, stream>>>(row_sum, col_sum, diag, out);
}

// Round 7
// 518.753 us; speedup vs baseline: 2.3634x; 2.3634x over previous
//
#include <hip/hip_runtime.h>
#include <hip/hip_bf16.h>
#include <stdint.h>

#define B_DIM 16384
#define D_DIM 512
#define INV_T (1.0f / 0.07f)

typedef __bf16 bf16x8 __attribute__((ext_vector_type(8)));
typedef float f32x4 __attribute__((ext_vector_type(4)));

typedef const __attribute__((address_space(1))) void* gptr_t;
typedef __attribute__((address_space(3))) void* lptr_t;

__device__ __forceinline__ uint16_t f32_to_bf16_rne(float x) {
  uint32_t b = __builtin_bit_cast(uint32_t, x);
  b += 0x7FFFu + ((b >> 16) & 1u);
  return (uint16_t)(b >> 16);
}

// One wave per row: load 512 fp32, L2-normalize, write 512 bf16 (row-major).
__global__ __launch_bounds__(256) void normalize_kernel(const float* __restrict__ in,
                                                        uint16_t* __restrict__ out) {
  int wid = threadIdx.x >> 6;
  int lane = threadIdx.x & 63;
  size_t row = (size_t)blockIdx.x * 4 + wid;
  const float* r = in + row * D_DIM;
  float4 v0 = ((const float4*)r)[lane * 2];
  float4 v1 = ((const float4*)r)[lane * 2 + 1];
  float ssq = v0.x * v0.x + v0.y * v0.y + v0.z * v0.z + v0.w * v0.w +
              v1.x * v1.x + v1.y * v1.y + v1.z * v1.z + v1.w * v1.w;
#pragma unroll
  for (int m = 1; m < 64; m <<= 1) ssq += __shfl_xor(ssq, m);
  float scale = 1.0f / fmaxf(sqrtf(ssq), 1e-12f);
  union {
    uint16_t u[8];
    uint4 v;
  } o;
  o.u[0] = f32_to_bf16_rne(v0.x * scale);
  o.u[1] = f32_to_bf16_rne(v0.y * scale);
  o.u[2] = f32_to_bf16_rne(v0.z * scale);
  o.u[3] = f32_to_bf16_rne(v0.w * scale);
  o.u[4] = f32_to_bf16_rne(v1.x * scale);
  o.u[5] = f32_to_bf16_rne(v1.y * scale);
  o.u[6] = f32_to_bf16_rne(v1.z * scale);
  o.u[7] = f32_to_bf16_rne(v1.w * scale);
  ((uint4*)(out + row * D_DIM))[lane] = o.v;
}

// m97-clone: 128x128 tile NT GEMM, 4 waves (2Mx2N), BK=32, 32 KB LDS total
// (double-buffered) -> ~3 blocks/CU co-residency (m114 overlap). Depth-1
// prefetch, one __syncthreads per K-tile. Conflict-free LDS: each fragment
// read is a contiguous 1 KB wave read. Fused exp + row/col sums + diag.
__global__ __launch_bounds__(256) void infonce_main(const uint16_t* __restrict__ P,
                                                    const uint16_t* __restrict__ T,
                                                    float* __restrict__ row_sum,
                                                    float* __restrict__ col_sum,
                                                    float* __restrict__ diag) {
  __shared__ __align__(16) uint16_t As[2][128][32];  // 16 KB
  __shared__ __align__(16) uint16_t Bs[2][128][32];  // 16 KB

  // XCD raster: xcd owns a 16-block-row strip (2048 rows = 2 MB A, L2-res);
  // within XCD, brow fastest -> concurrent blocks share bcol tiles.
  int bid = blockIdx.x;          // 0..16383
  int xcd = bid & 7;
  int q = bid >> 3;              // 0..2047
  int brow = (xcd * 16 + (q & 15)) << 7;
  int bcol = (q >> 4) << 7;

  int tid = threadIdx.x;
  int lane = tid & 63;
  int wid = tid >> 6;
  int wr = (wid >> 1) * 64;      // 2 M-waves
  int wc = (wid & 1) * 64;       // 2 N-waves
  int rlane = lane >> 4;
  int clane = lane & 15;

  f32x4 acc[4][4] = {};

  // Stage one 128x32 K-tile (8 KB/array): 2 x gload_lds(16B)/thread, linear.
#define STAGE(buf, kt)                                                         \
  do {                                                                         \
    _Pragma("unroll") for (int it = 0; it < 2; ++it) {                         \
      int l = it * 256 + tid;                                                  \
      int r = l >> 2;                                                          \
      int c = (l & 3) << 3;                                                    \
      __builtin_amdgcn_global_load_lds(                                        \
          (gptr_t)(P + (size_t)(brow + r) * D_DIM + (kt) * 32 + c),            \
          (lptr_t)(&As[buf][0][0] + (size_t)l * 8), 16, 0, 0);                 \
      __builtin_amdgcn_global_load_lds(                                        \
          (gptr_t)(T + (size_t)(bcol + r) * D_DIM + (kt) * 32 + c),            \
          (lptr_t)(&Bs[buf][0][0] + (size_t)l * 8), 16, 0, 0);                 \
    }                                                                          \
  } while (0)

  STAGE(0, 0);
  __syncthreads();  // drain: buf0 ready

#pragma unroll
  for (int t = 0; t < 16; ++t) {
    const int cur = t & 1;
    if (t < 15) STAGE(cur ^ 1, t + 1);  // prefetch next tile, in flight over MFMA
    bf16x8 a[4], b[4];
#pragma unroll
    for (int m = 0; m < 4; ++m)
      a[m] = *(const bf16x8*)(&As[cur][wr + m * 16 + clane][rlane * 8]);
#pragma unroll
    for (int n = 0; n < 4; ++n)
      b[n] = *(const bf16x8*)(&Bs[cur][wc + n * 16 + clane][rlane * 8]);
#pragma unroll
    for (int m = 0; m < 4; ++m)
#pragma unroll
      for (int n = 0; n < 4; ++n)
        acc[m][n] = __builtin_amdgcn_mfma_f32_16x16x32_bf16(a[m], b[n], acc[m][n], 0, 0, 0);
    __syncthreads();  // drains lgkm (reads of cur) + vmcnt (stage of cur^1)
  }
#undef STAGE

  // Epilogue: logit = acc/T; capture diagonal; exponentiate in place.
#pragma unroll
  for (int m = 0; m < 4; ++m)
#pragma unroll
    for (int n = 0; n < 4; ++n)
#pragma unroll
      for (int j = 0; j < 4; ++j) {
        float logit = acc[m][n][j] * INV_T;
        int grow = brow + wr + m * 16 + rlane * 4 + j;
        int gcol = bcol + wc + n * 16 + clane;
        if (grow == gcol) diag[grow] = logit;
        acc[m][n][j] = __expf(logit);
      }

  // Row sums: reduce over n-fragments then across the 16-lane column group.
#pragma unroll
  for (int m = 0; m < 4; ++m)
#pragma unroll
    for (int j = 0; j < 4; ++j) {
      float rs = acc[m][0][j] + acc[m][1][j] + acc[m][2][j] + acc[m][3][j];
      rs += __shfl_xor(rs, 1);
      rs += __shfl_xor(rs, 2);
      rs += __shfl_xor(rs, 4);
      rs += __shfl_xor(rs, 8);
      if (clane == 0) atomicAdd(&row_sum[brow + wr + m * 16 + rlane * 4 + j], rs);
    }

  // Col sums: reduce over m-fragments and regs, then across the 4 row groups.
#pragma unroll
  for (int n = 0; n < 4; ++n) {
    float cs = 0.f;
#pragma unroll
    for (int m = 0; m < 4; ++m)
#pragma unroll
      for (int j = 0; j < 4; ++j) cs += acc[m][n][j];
    cs += __shfl_xor(cs, 16);
    cs += __shfl_xor(cs, 32);
    if (rlane == 0) atomicAdd(&col_sum[bcol + wc + n * 16 + clane], cs);
  }
}

__global__ __launch_bounds__(256) void finalize_kernel(const float* __restrict__ rs,
                                                       const float* __restrict__ cs,
                                                       const float* __restrict__ dg,
                                                       float* __restrict__ out) {
  float s = 0.f;
  for (int i = threadIdx.x; i < B_DIM; i += 256)
    s += 0.5f * (logf(rs[i]) + logf(cs[i])) - dg[i];
#pragma unroll
  for (int m = 1; m < 64; m <<= 1) s += __shfl_xor(s, m);
  __shared__ float red[4];
  if ((threadIdx.x & 63) == 0) red[threadIdx.x >> 6] = s;
  __syncthreads();
  if (threadIdx.x == 0)
    out[0] = (red[0] + red[1] + red[2] + red[3]) * (1.0f / (float)B_DIM);
}

extern "C" void kernel_launch(void* const* d_in, const int* in_sizes, int n_in,
                              void* d_out, int out_size, void* d_ws, size_t ws_size,
                              hipStream_t stream) {
  const float* p = (const float*)d_in[0];
  const float* t = (const float*)d_in[1];
  float* out = (float*)d_out;

  char* ws = (char*)d_ws;
  const size_t embBytes = (size_t)B_DIM * D_DIM * sizeof(uint16_t);  // 16 MB
  uint16_t* Pn = (uint16_t*)ws;
  uint16_t* Tn = (uint16_t*)(ws + embBytes);
  float* row_sum = (float*)(ws + 2 * embBytes);
  float* col_sum = row_sum + B_DIM;
  float* diag = col_sum + B_DIM;

  hipMemsetAsync(row_sum, 0, 2 * (size_t)B_DIM * sizeof(float), stream);
  normalize_kernel<<<B_DIM / 4, 256, 0, stream>>>(p, Pn);
  normalize_kernel<<<B_DIM / 4, 256, 0, stream>>>(t, Tn);
  infonce_main<<<(B_DIM / 128) * (B_DIM / 128), 256, 0, stream>>>(Pn, Tn, row_sum, col_sum, diag);
  finalize_kernel<<<1, 256, 0, stream>>>(row_sum, col_sum, diag, out);
}

// Round 8
// 406.560 us; speedup vs baseline: 3.0156x; 1.2760x over previous
//
#include <hip/hip_runtime.h>
#include <hip/hip_bf16.h>
#include <stdint.h>

#define B_DIM 16384
#define D_DIM 512
#define INV_T (1.0f / 0.07f)

typedef __bf16 bf16x8 __attribute__((ext_vector_type(8)));
typedef float f32x4 __attribute__((ext_vector_type(4)));

typedef const __attribute__((address_space(1))) void* gptr_t;
typedef __attribute__((address_space(3))) void* lptr_t;

__device__ __forceinline__ uint16_t f32_to_bf16_rne(float x) {
  uint32_t b = __builtin_bit_cast(uint32_t, x);
  b += 0x7FFFu + ((b >> 16) & 1u);
  return (uint16_t)(b >> 16);
}

// Fragment-linear global layout (identical for Pn and Tn):
//   chunk(RB,KT) = ((RB*8)+KT)*16384 bytes   // RB = row>>7, KT = k>>6
//   inside: subtile (kk = (k>>5)&1, mq = (row>>4)&7) -> 1 KB at (kk*8+mq)*1024
//           slot: lane = rlane*16 + clane (rlane=(k>>3)&3, clane=row&15)
//                 -> (rlane*16+clane)*16 + (k&7)*2
// => GEMM staging of any (128-row, 64-k) half is a contiguous 16-KB copy, and
//    every MFMA fragment ds_read_b128 is a contiguous 1-KB wave read (lane*16):
//    ZERO bank conflicts (r6-proven pattern), m104-safe linear gload_lds dest.

// One wave per row: load 512 fp32, L2-normalize, write 64x 16-B fragment slots.
__global__ __launch_bounds__(256) void normalize_kernel(const float* __restrict__ in,
                                                        uint16_t* __restrict__ out) {
  int wid = threadIdx.x >> 6;
  int lane = threadIdx.x & 63;
  int row = blockIdx.x * 4 + wid;
  const float* r = in + (size_t)row * D_DIM;
  float4 v0 = ((const float4*)r)[lane * 2];
  float4 v1 = ((const float4*)r)[lane * 2 + 1];
  float ssq = v0.x * v0.x + v0.y * v0.y + v0.z * v0.z + v0.w * v0.w +
              v1.x * v1.x + v1.y * v1.y + v1.z * v1.z + v1.w * v1.w;
#pragma unroll
  for (int m = 1; m < 64; m <<= 1) ssq += __shfl_xor(ssq, m);
  float scale = 1.0f / fmaxf(sqrtf(ssq), 1e-12f);
  union {
    uint16_t u[8];
    uint4 v;
  } o;
  o.u[0] = f32_to_bf16_rne(v0.x * scale);
  o.u[1] = f32_to_bf16_rne(v0.y * scale);
  o.u[2] = f32_to_bf16_rne(v0.z * scale);
  o.u[3] = f32_to_bf16_rne(v0.w * scale);
  o.u[4] = f32_to_bf16_rne(v1.x * scale);
  o.u[5] = f32_to_bf16_rne(v1.y * scale);
  o.u[6] = f32_to_bf16_rne(v1.z * scale);
  o.u[7] = f32_to_bf16_rne(v1.w * scale);
  // lane covers k = lane*8 .. lane*8+7
  size_t chunk = ((size_t)(row >> 7) * 8 + (lane >> 3)) * 16384;
  int kk = (lane >> 2) & 1, mq = (row >> 4) & 7;
  int rl = lane & 3, cl = row & 15;
  size_t addr = chunk + (size_t)(kk * 8 + mq) * 1024 + (rl * 16 + cl) * 16;
  *(uint4*)((char*)out + addr) = o.v;
}

// 256x256 tile NT GEMM, 8 waves (2Mx4N), BK=64, r4's 4-phase quadrant
// schedule + counted-vmcnt ledger, fragment-linear LDS (zero conflicts).
// Fused exp + row/col sums + diag.
__global__ __launch_bounds__(512, 2) void infonce_main(const uint16_t* __restrict__ P,
                                                       const uint16_t* __restrict__ T,
                                                       float* __restrict__ row_sum,
                                                       float* __restrict__ col_sum,
                                                       float* __restrict__ diag) {
  // [dbuf][M-half][16 KB fragment-linear half-tile]
  __shared__ __align__(16) uint16_t As[2][2][8192];  // 64 KB
  __shared__ __align__(16) uint16_t Bs[2][2][8192];  // 64 KB

  int bid = blockIdx.x;  // 4096; r2-r4 raster (74 MB FETCH proven)
  int xcd = bid & 7;
  int q = bid >> 3;
  int brow = (xcd * 8 + (q & 7)) << 8;
  int bcol = (q >> 3) << 8;

  int tid = threadIdx.x;
  int lane = tid & 63;
  int wid = tid >> 6;
  int wr = (wid >> 2) * 128;  // 2 M-wave groups
  int wc = (wid & 3) * 64;    // 4 N-waves
  int rlane = lane >> 4;
  int clane = lane & 15;
  int haA = wid >> 2;         // wave's A half
  int haB = (wid >> 1) & 1;   // wave's B half
  int nbase = (wid & 1) * 4;  // 16-row-group base within B half

  f32x4 acc[8][4] = {};

  // Stage one 16-KB half-tile: pure linear copy, 2 x gload_lds(16B)/thread.
#define STAGE_HALF(ARR, SRC, RBASE, BUF, H, KT)                                \
  do {                                                                         \
    size_t base_ = ((size_t)(((RBASE) >> 7) + (H)) * 8 + (KT)) * 16384;        \
    _Pragma("unroll") for (int it = 0; it < 2; ++it) {                         \
      int s_ = it * 512 + tid;                                                 \
      __builtin_amdgcn_global_load_lds(                                        \
          (gptr_t)((const char*)(SRC) + base_ + (size_t)s_ * 16),              \
          (lptr_t)((char*)&ARR[BUF][H][0] + (size_t)s_ * 16), 16, 0, 0);       \
    }                                                                          \
  } while (0)

  // Lane-linear fragment reads: ds_read_b128 at byte offset sub*1024 + lane*16.
#define RD_A(dst, BUF, MH)                                                     \
  _Pragma("unroll") for (int mq = 0; mq < 4; ++mq)                             \
      _Pragma("unroll") for (int kk = 0; kk < 2; ++kk) dst[mq][kk] =           \
      *(const bf16x8*)(&As[BUF][haA][(kk * 8 + (MH)*4 + mq) * 512 + lane * 8])

#define RD_B(dst, BUF, NP)                                                     \
  _Pragma("unroll") for (int np = 0; np < 2; ++np)                             \
      _Pragma("unroll") for (int kk = 0; kk < 2; ++kk) dst[np][kk] =           \
      *(const bf16x8*)(&Bs[BUF][haB][(kk * 8 + nbase + (NP)*2 + np) * 512 +    \
                                     lane * 8])

#define MM_Q(MH, NP, aa, bb)                                                   \
  _Pragma("unroll") for (int mq = 0; mq < 4; ++mq)                             \
      _Pragma("unroll") for (int np = 0; np < 2; ++np)                         \
          _Pragma("unroll") for (int kk = 0; kk < 2; ++kk)                     \
              acc[(MH)*4 + mq][(NP)*2 + np] =                                  \
      __builtin_amdgcn_mfma_f32_16x16x32_bf16(aa[mq][kk], bb[np][kk],          \
                                              acc[(MH)*4 + mq][(NP)*2 + np],   \
                                              0, 0, 0)

#define MFMA_WRAP(X)                                                           \
  __builtin_amdgcn_s_barrier();                                                \
  __builtin_amdgcn_s_setprio(1);                                               \
  X;                                                                           \
  __builtin_amdgcn_s_setprio(0);                                               \
  __builtin_amdgcn_s_barrier()

  // Prologue: A0(0),B0(0),A1(0),B1(0),A0(1) staged; confirm tile 0's halves
  // at the first vmcnt below (prologue issues 10 loads; first phase waits
  // vmcnt(2) -> 8 oldest done = all of tile 0 + A0(1) partly).
  STAGE_HALF(As, P, brow, 0, 0, 0);
  STAGE_HALF(Bs, T, bcol, 0, 0, 0);
  STAGE_HALF(As, P, brow, 0, 1, 0);
  STAGE_HALF(Bs, T, bcol, 0, 1, 0);
  STAGE_HALF(As, P, brow, 1, 0, 1);

#pragma unroll
  for (int t = 0; t < 8; ++t) {
    const int CB = t & 1, NB = (t + 1) & 1;
    bf16x8 a0[4][2], a1[4][2], b0[2][2], b1[2][2], b0r[2][2];
    // Ledger (r4-verified): issue B0(t+1)@p1, A1(t+1)@p2, B1(t+1)@p3,
    // A0(t+2)@p4. vmcnt(2)@p1 confirms all of tile t; vmcnt tightens at tail.
    // ---- p1: Q(0,0) ----
    if (t == 7) asm volatile("s_waitcnt vmcnt(0)" ::: "memory");
    else        asm volatile("s_waitcnt vmcnt(2)" ::: "memory");
    RD_A(a0, CB, 0);
    RD_B(b0, CB, 0);
    if (t < 7) STAGE_HALF(Bs, T, bcol, NB, 0, t + 1);
    MFMA_WRAP(MM_Q(0, 0, a0, b0));
    // ---- p2: Q(0,1), reuse a0 ----
    RD_B(b1, CB, 1);
    if (t < 7) STAGE_HALF(As, P, brow, NB, 1, t + 1);
    MFMA_WRAP(MM_Q(0, 1, a0, b1));
    // ---- p3: Q(1,1), reuse b1 ----
    RD_A(a1, CB, 1);
    if (t < 7) STAGE_HALF(Bs, T, bcol, NB, 1, t + 1);
    MFMA_WRAP(MM_Q(1, 1, a1, b1));
    // ---- p4: Q(1,0), re-read b0 ----
    RD_B(b0r, CB, 0);
    if (t < 6) STAGE_HALF(As, P, brow, CB, 0, t + 2);
    MFMA_WRAP(MM_Q(1, 0, a1, b0r));
  }
#undef STAGE_HALF
#undef RD_A
#undef RD_B
#undef MM_Q
#undef MFMA_WRAP

  // Epilogue: logit = acc/T; capture diagonal; exponentiate in place.
#pragma unroll
  for (int m = 0; m < 8; ++m)
#pragma unroll
    for (int n = 0; n < 4; ++n)
#pragma unroll
      for (int j = 0; j < 4; ++j) {
        float logit = acc[m][n][j] * INV_T;
        int grow = brow + wr + m * 16 + rlane * 4 + j;
        int gcol = bcol + wc + n * 16 + clane;
        if (grow == gcol) diag[grow] = logit;
        acc[m][n][j] = __expf(logit);
      }

  // Row sums: reduce over n-fragments then across the 16-lane column group.
#pragma unroll
  for (int m = 0; m < 8; ++m)
#pragma unroll
    for (int j = 0; j < 4; ++j) {
      float rs = acc[m][0][j] + acc[m][1][j] + acc[m][2][j] + acc[m][3][j];
      rs += __shfl_xor(rs, 1);
      rs += __shfl_xor(rs, 2);
      rs += __shfl_xor(rs, 4);
      rs += __shfl_xor(rs, 8);
      if (clane == 0) atomicAdd(&row_sum[brow + wr + m * 16 + rlane * 4 + j], rs);
    }

  // Col sums: reduce over m-fragments and regs, then across the 4 row groups.
#pragma unroll
  for (int n = 0; n < 4; ++n) {
    float cs = 0.f;
#pragma unroll
    for (int m = 0; m < 8; ++m)
#pragma unroll
      for (int j = 0; j < 4; ++j) cs += acc[m][n][j];
    cs += __shfl_xor(cs, 16);
    cs += __shfl_xor(cs, 32);
    if (rlane == 0) atomicAdd(&col_sum[bcol + wc + n * 16 + clane], cs);
  }
}

__global__ __launch_bounds__(256) void finalize_kernel(const float* __restrict__ rs,
                                                       const float* __restrict__ cs,
                                                       const float* __restrict__ dg,
                                                       float* __restrict__ out) {
  float s = 0.f;
  for (int i = threadIdx.x; i < B_DIM; i += 256)
    s += 0.5f * (logf(rs[i]) + logf(cs[i])) - dg[i];
#pragma unroll
  for (int m = 1; m < 64; m <<= 1) s += __shfl_xor(s, m);
  __shared__ float red[4];
  if ((threadIdx.x & 63) == 0) red[threadIdx.x >> 6] = s;
  __syncthreads();
  if (threadIdx.x == 0)
    out[0] = (red[0] + red[1] + red[2] + red[3]) * (1.0f / (float)B_DIM);
}

extern "C" void kernel_launch(void* const* d_in, const int* in_sizes, int n_in,
                              void* d_out, int out_size, void* d_ws, size_t ws_size,
                              hipStream_t stream) {
  const float* p = (const float*)d_in[0];
  const float* t = (const float*)d_in[1];
  float* out = (float*)d_out;

  char* ws = (char*)d_ws;
  const size_t embBytes = (size_t)B_DIM * D_DIM * sizeof(uint16_t);  // 16 MB
  uint16_t* Pn = (uint16_t*)ws;
  uint16_t* Tn = (uint16_t*)(ws + embBytes);
  float* row_sum = (float*)(ws + 2 * embBytes);
  float* col_sum = row_sum + B_DIM;
  float* diag = col_sum + B_DIM;

  hipMemsetAsync(row_sum, 0, 2 * (size_t)B_DIM * sizeof(float), stream);
  normalize_kernel<<<B_DIM / 4, 256, 0, stream>>>(p, Pn);
  normalize_kernel<<<B_DIM / 4, 256, 0, stream>>>(t, Tn);
  infonce_main<<<(B_DIM / 256) * (B_DIM / 256), 512, 0, stream>>>(Pn, Tn, row_sum, col_sum, diag);
  finalize_kernel<<<1, 256, 0, stream>>>(row_sum, col_sum, diag, out);
}

// Round 9
// 404.680 us; speedup vs baseline: 3.0296x; 1.0046x over previous
//
#include <hip/hip_runtime.h>
#include <hip/hip_bf16.h>
#include <stdint.h>

#define B_DIM 16384
#define D_DIM 512
// Embeddings quantized as fp8(8*x): dot scales by 64. logit = dot/64/T.
#define LOGIT_SCALE (1.0f / (0.07f * 64.0f))

typedef int i32x4 __attribute__((ext_vector_type(4)));
typedef float f32x4 __attribute__((ext_vector_type(4)));

typedef const __attribute__((address_space(1))) void* gptr_t;
typedef __attribute__((address_space(3))) void* lptr_t;

// Fragment-linear fp8 layout (identical for Pn and Tn), BK=64 chunks:
//   chunk(RB = row>>7, KT = k>>6) = (RB*8 + KT)*8192 bytes   (128 rows x 64 k)
//   subtile mq = (row>>4)&7 -> 1 KB at mq*1024
//   slot lane = ((k>>3)&3)*16 + (row&15) -> 16 B at lane*16
//   byte: kb = (k>>5)&1 -> + kb*8 + (k&7)
// => fp8 16x16x32 MFMA fragment (lane = rlane*16+clane holds k=rlane*8..+7,
//    kk=0 in bytes 0..7, kk=1 in bytes 8..15) is ONE ds_read_b128 at lane*16:
//    zero bank conflicts; staging any chunk is a pure linear 8-KB copy.

// One wave per row: load 512 fp32, L2-normalize, scale by 8, quantize e4m3,
// write one 8-B fragment slot per lane.
__global__ __launch_bounds__(256) void normalize_kernel(const float* __restrict__ in,
                                                        uint8_t* __restrict__ out) {
  int wid = threadIdx.x >> 6;
  int lane = threadIdx.x & 63;
  int row = blockIdx.x * 4 + wid;
  const float* r = in + (size_t)row * D_DIM;
  float4 v0 = ((const float4*)r)[lane * 2];
  float4 v1 = ((const float4*)r)[lane * 2 + 1];
  float ssq = v0.x * v0.x + v0.y * v0.y + v0.z * v0.z + v0.w * v0.w +
              v1.x * v1.x + v1.y * v1.y + v1.z * v1.z + v1.w * v1.w;
#pragma unroll
  for (int m = 1; m < 64; m <<= 1) ssq += __shfl_xor(ssq, m);
  float s8 = 8.0f / fmaxf(sqrtf(ssq), 1e-12f);
  int w0 = __builtin_amdgcn_cvt_pk_fp8_f32(v0.x * s8, v0.y * s8, 0, false);
  w0 = __builtin_amdgcn_cvt_pk_fp8_f32(v0.z * s8, v0.w * s8, w0, true);
  int w1 = __builtin_amdgcn_cvt_pk_fp8_f32(v1.x * s8, v1.y * s8, 0, false);
  w1 = __builtin_amdgcn_cvt_pk_fp8_f32(v1.z * s8, v1.w * s8, w1, true);
  // lane covers k = lane*8 .. lane*8+7
  int KT = lane >> 3, kb = (lane >> 2) & 1, rl = lane & 3;
  int mq = (row >> 4) & 7, cl = row & 15;
  size_t addr = ((size_t)(row >> 7) * 8 + KT) * 8192 + (size_t)mq * 1024 +
                (rl * 16 + cl) * 16 + kb * 8;
  uint2 o;
  o.x = (unsigned)w0;
  o.y = (unsigned)w1;
  *(uint2*)(out + addr) = o;
}

// fp8 128x128-tile NT GEMM (m145 family): 4 waves (2Mx2N), BK=64, 32 KB LDS
// double-buffered -> ~3 blocks/CU co-residency (m114 overlap). Depth-1
// prefetch, one __syncthreads per K-tile, 32 MFMA/wave between barriers.
// Fragment-linear LDS: zero bank conflicts. Fused exp + row/col sums + diag.
__global__ __launch_bounds__(256) void infonce_main(const uint8_t* __restrict__ P,
                                                    const uint8_t* __restrict__ T,
                                                    float* __restrict__ row_sum,
                                                    float* __restrict__ col_sum,
                                                    float* __restrict__ diag) {
  __shared__ __align__(16) uint8_t As[2][8192];  // 16 KB
  __shared__ __align__(16) uint8_t Bs[2][8192];  // 16 KB

  // XCD raster (r2-proven): xcd owns 16 brow strips (2048 rows = 1 MB fp8 A,
  // L2-resident); within XCD, brow fastest -> concurrent blocks share bcol.
  int bid = blockIdx.x;          // 0..16383
  int xcd = bid & 7;
  int q = bid >> 3;              // 0..2047
  int brow = (xcd * 16 + (q & 15)) << 7;
  int bcol = (q >> 4) << 7;

  int tid = threadIdx.x;
  int lane = tid & 63;
  int wid = tid >> 6;
  int wr = (wid >> 1) * 64;      // 2 M-waves
  int wc = (wid & 1) * 64;       // 2 N-waves
  int rlane = lane >> 4;
  int clane = lane & 15;

  f32x4 acc[4][4] = {};

  // Stage one K-tile (8 KB per array): 2 x gload_lds(16B)/thread, pure linear.
#define STAGE(buf, kt)                                                         \
  do {                                                                         \
    size_t baseA = ((size_t)(brow >> 7) * 8 + (kt)) * 8192;                    \
    size_t baseB = ((size_t)(bcol >> 7) * 8 + (kt)) * 8192;                    \
    _Pragma("unroll") for (int it = 0; it < 2; ++it) {                         \
      int s = it * 256 + tid;                                                  \
      __builtin_amdgcn_global_load_lds((gptr_t)(P + baseA + (size_t)s * 16),   \
                                       (lptr_t)(&As[buf][0] + s * 16), 16, 0,  \
                                       0);                                     \
      __builtin_amdgcn_global_load_lds((gptr_t)(T + baseB + (size_t)s * 16),   \
                                       (lptr_t)(&Bs[buf][0] + s * 16), 16, 0,  \
                                       0);                                     \
    }                                                                          \
  } while (0)

  STAGE(0, 0);
  __syncthreads();  // buf0 ready

#pragma unroll
  for (int t = 0; t < 8; ++t) {
    const int cur = t & 1;
    if (t < 7) STAGE(cur ^ 1, t + 1);  // prefetch next tile over this MFMA burst
    i32x4 av[4], bv[4];
#pragma unroll
    for (int m = 0; m < 4; ++m)
      av[m] = *(const i32x4*)(&As[cur][((wid >> 1) * 4 + m) * 1024 + lane * 16]);
#pragma unroll
    for (int n = 0; n < 4; ++n)
      bv[n] = *(const i32x4*)(&Bs[cur][((wid & 1) * 4 + n) * 1024 + lane * 16]);
#pragma unroll
    for (int m = 0; m < 4; ++m) {
      long long alo = __builtin_bit_cast(long long, (int2){av[m].x, av[m].y});
      long long ahi = __builtin_bit_cast(long long, (int2){av[m].z, av[m].w});
#pragma unroll
      for (int n = 0; n < 4; ++n) {
        long long blo = __builtin_bit_cast(long long, (int2){bv[n].x, bv[n].y});
        long long bhi = __builtin_bit_cast(long long, (int2){bv[n].z, bv[n].w});
        acc[m][n] = __builtin_amdgcn_mfma_f32_16x16x32_fp8_fp8(alo, blo, acc[m][n], 0, 0, 0);
        acc[m][n] = __builtin_amdgcn_mfma_f32_16x16x32_fp8_fp8(ahi, bhi, acc[m][n], 0, 0, 0);
      }
    }
    __syncthreads();  // drains lgkm (reads of cur) + vmcnt (stage of cur^1)
  }
#undef STAGE

  // Epilogue: logit = acc*LOGIT_SCALE; capture diagonal; exp in place.
#pragma unroll
  for (int m = 0; m < 4; ++m)
#pragma unroll
    for (int n = 0; n < 4; ++n)
#pragma unroll
      for (int j = 0; j < 4; ++j) {
        float logit = acc[m][n][j] * LOGIT_SCALE;
        int grow = brow + wr + m * 16 + rlane * 4 + j;
        int gcol = bcol + wc + n * 16 + clane;
        if (grow == gcol) diag[grow] = logit;
        acc[m][n][j] = __expf(logit);
      }

  // Row sums: reduce over n-fragments then across the 16-lane column group.
#pragma unroll
  for (int m = 0; m < 4; ++m)
#pragma unroll
    for (int j = 0; j < 4; ++j) {
      float rs = acc[m][0][j] + acc[m][1][j] + acc[m][2][j] + acc[m][3][j];
      rs += __shfl_xor(rs, 1);
      rs += __shfl_xor(rs, 2);
      rs += __shfl_xor(rs, 4);
      rs += __shfl_xor(rs, 8);
      if (clane == 0) atomicAdd(&row_sum[brow + wr + m * 16 + rlane * 4 + j], rs);
    }

  // Col sums: reduce over m-fragments and regs, then across the 4 row groups.
#pragma unroll
  for (int n = 0; n < 4; ++n) {
    float cs = 0.f;
#pragma unroll
    for (int m = 0; m < 4; ++m)
#pragma unroll
      for (int j = 0; j < 4; ++j) cs += acc[m][n][j];
    cs += __shfl_xor(cs, 16);
    cs += __shfl_xor(cs, 32);
    if (rlane == 0) atomicAdd(&col_sum[bcol + wc + n * 16 + clane], cs);
  }
}

__global__ __launch_bounds__(256) void finalize_kernel(const float* __restrict__ rs,
                                                       const float* __restrict__ cs,
                                                       const float* __restrict__ dg,
                                                       float* __restrict__ out) {
  float s = 0.f;
  for (int i = threadIdx.x; i < B_DIM; i += 256)
    s += 0.5f * (logf(rs[i]) + logf(cs[i])) - dg[i];
#pragma unroll
  for (int m = 1; m < 64; m <<= 1) s += __shfl_xor(s, m);
  __shared__ float red[4];
  if ((threadIdx.x & 63) == 0) red[threadIdx.x >> 6] = s;
  __syncthreads();
  if (threadIdx.x == 0)
    out[0] = (red[0] + red[1] + red[2] + red[3]) * (1.0f / (float)B_DIM);
}

extern "C" void kernel_launch(void* const* d_in, const int* in_sizes, int n_in,
                              void* d_out, int out_size, void* d_ws, size_t ws_size,
                              hipStream_t stream) {
  const float* p = (const float*)d_in[0];
  const float* t = (const float*)d_in[1];
  float* out = (float*)d_out;

  char* ws = (char*)d_ws;
  const size_t embBytes = (size_t)B_DIM * D_DIM;  // 8 MB fp8
  uint8_t* Pn = (uint8_t*)ws;
  uint8_t* Tn = (uint8_t*)(ws + embBytes);
  float* row_sum = (float*)(ws + 2 * embBytes);
  float* col_sum = row_sum + B_DIM;
  float* diag = col_sum + B_DIM;

  hipMemsetAsync(row_sum, 0, 2 * (size_t)B_DIM * sizeof(float), stream);
  normalize_kernel<<<B_DIM / 4, 256, 0, stream>>>(p, Pn);
  normalize_kernel<<<B_DIM / 4, 256, 0, stream>>>(t, Tn);
  infonce_main<<<(B_DIM / 128) * (B_DIM / 128), 256, 0, stream>>>(Pn, Tn, row_sum, col_sum, diag);
  finalize_kernel<<<1, 256, 0, stream>>>(row_sum, col_sum, diag, out);
}

// Round 10
// 266.819 us; speedup vs baseline: 4.5950x; 1.5167x over previous
//
#include <hip/hip_runtime.h>
#include <hip/hip_bf16.h>
#include <stdint.h>

#define B_DIM 16384
#define D_DIM 512
// Embeddings quantized as fp8(8*x): dot scales by 64. logit = dot/64/T.
#define LOGIT_SCALE (1.0f / (0.07f * 64.0f))

typedef int i32x4 __attribute__((ext_vector_type(4)));
typedef float f32x4 __attribute__((ext_vector_type(4)));

// Fragment-linear fp8 layout (identical for Pn and Tn), BK=64 chunks:
//   chunk(RB = row>>7, KT = k>>6) = (RB*8 + KT)*8192 bytes   (128 rows x 64 k)
//   subtile mq = (row>>4)&7 -> 1 KB at mq*1024
//   slot lane = ((k>>3)&3)*16 + (row&15) -> 16 B at lane*16
//   byte: kb = (k>>5)&1 -> + kb*8 + (k&7)
// => fp8 16x16x32 MFMA fragment = ONE contiguous 1-KB wave read — a single
//    perfectly-coalesced global_load_dwordx4 (no LDS needed at all).

// One wave per row: load 512 fp32, L2-normalize, scale by 8, quantize e4m3,
// write one 8-B fragment slot per lane. (r9-proven.)
__global__ __launch_bounds__(256) void normalize_kernel(const float* __restrict__ in,
                                                        uint8_t* __restrict__ out) {
  int wid = threadIdx.x >> 6;
  int lane = threadIdx.x & 63;
  int row = blockIdx.x * 4 + wid;
  const float* r = in + (size_t)row * D_DIM;
  float4 v0 = ((const float4*)r)[lane * 2];
  float4 v1 = ((const float4*)r)[lane * 2 + 1];
  float ssq = v0.x * v0.x + v0.y * v0.y + v0.z * v0.z + v0.w * v0.w +
              v1.x * v1.x + v1.y * v1.y + v1.z * v1.z + v1.w * v1.w;
#pragma unroll
  for (int m = 1; m < 64; m <<= 1) ssq += __shfl_xor(ssq, m);
  float s8 = 8.0f / fmaxf(sqrtf(ssq), 1e-12f);
  int w0 = __builtin_amdgcn_cvt_pk_fp8_f32(v0.x * s8, v0.y * s8, 0, false);
  w0 = __builtin_amdgcn_cvt_pk_fp8_f32(v0.z * s8, v0.w * s8, w0, true);
  int w1 = __builtin_amdgcn_cvt_pk_fp8_f32(v1.x * s8, v1.y * s8, 0, false);
  w1 = __builtin_amdgcn_cvt_pk_fp8_f32(v1.z * s8, v1.w * s8, w1, true);
  // lane covers k = lane*8 .. lane*8+7
  int KT = lane >> 3, kb = (lane >> 2) & 1, rl = lane & 3;
  int mq = (row >> 4) & 7, cl = row & 15;
  size_t addr = ((size_t)(row >> 7) * 8 + KT) * 8192 + (size_t)mq * 1024 +
                (rl * 16 + cl) * 16 + kb * 8;
  uint2 o;
  o.x = (unsigned)w0;
  o.y = (unsigned)w1;
  *(uint2*)(out + addr) = o;
}

// LDS-free fp8 128x128-tile NT GEMM: 4 waves (2Mx2N), each wave 64x64 out.
// Fragments loaded straight from L2 (fragment-linear layout = coalesced
// 1-KB wave reads). Zero barriers, zero LDS: waves fully independent ->
// pure TLP/ILP latency hiding (m114). Depth-1 register double-buffer,
// static indices. Fused exp + row/col sums + diag.
__global__ __launch_bounds__(256, 3) void infonce_main(const uint8_t* __restrict__ P,
                                                       const uint8_t* __restrict__ T,
                                                       float* __restrict__ row_sum,
                                                       float* __restrict__ col_sum,
                                                       float* __restrict__ diag) {
  // XCD raster (r2-proven): xcd owns 16 brow strips (2048 rows = 1 MB fp8 A,
  // L2-resident); within XCD, brow fastest -> concurrent blocks share bcol.
  int bid = blockIdx.x;          // 0..16383
  int xcd = bid & 7;
  int q = bid >> 3;              // 0..2047
  int brow = (xcd * 16 + (q & 15)) << 7;
  int bcol = (q >> 4) << 7;

  int tid = threadIdx.x;
  int lane = tid & 63;
  int wid = tid >> 6;
  int wr = (wid >> 1) * 64;      // 2 M-waves
  int wc = (wid & 1) * 64;       // 2 N-waves
  int rlane = lane >> 4;
  int clane = lane & 15;

  // Wave's fragment base pointers (fragment m/n at K-tile kt: + kt*8192 + m*1024).
  const uint8_t* pA = P + ((size_t)(brow >> 7) * 8) * 8192 +
                      (size_t)((wid >> 1) * 4) * 1024 + (size_t)lane * 16;
  const uint8_t* pB = T + ((size_t)(bcol >> 7) * 8) * 8192 +
                      (size_t)((wid & 1) * 4) * 1024 + (size_t)lane * 16;

  f32x4 acc[4][4] = {};

  i32x4 a[4], b[4];
#pragma unroll
  for (int m = 0; m < 4; ++m) a[m] = *(const i32x4*)(pA + m * 1024);
#pragma unroll
  for (int n = 0; n < 4; ++n) b[n] = *(const i32x4*)(pB + n * 1024);

#pragma unroll
  for (int t = 0; t < 8; ++t) {
    i32x4 an[4], bn[4];
    if (t < 7) {
#pragma unroll
      for (int m = 0; m < 4; ++m)
        an[m] = *(const i32x4*)(pA + (t + 1) * 8192 + m * 1024);
#pragma unroll
      for (int n = 0; n < 4; ++n)
        bn[n] = *(const i32x4*)(pB + (t + 1) * 8192 + n * 1024);
    }
#pragma unroll
    for (int m = 0; m < 4; ++m) {
      long long alo = __builtin_bit_cast(long long, (int2){a[m].x, a[m].y});
      long long ahi = __builtin_bit_cast(long long, (int2){a[m].z, a[m].w});
#pragma unroll
      for (int n = 0; n < 4; ++n) {
        long long blo = __builtin_bit_cast(long long, (int2){b[n].x, b[n].y});
        long long bhi = __builtin_bit_cast(long long, (int2){b[n].z, b[n].w});
        acc[m][n] = __builtin_amdgcn_mfma_f32_16x16x32_fp8_fp8(alo, blo, acc[m][n], 0, 0, 0);
        acc[m][n] = __builtin_amdgcn_mfma_f32_16x16x32_fp8_fp8(ahi, bhi, acc[m][n], 0, 0, 0);
      }
    }
    if (t < 7) {
#pragma unroll
      for (int m = 0; m < 4; ++m) a[m] = an[m];
#pragma unroll
      for (int n = 0; n < 4; ++n) b[n] = bn[n];
    }
  }

  // Epilogue: logit = acc*LOGIT_SCALE; capture diagonal; exp in place.
#pragma unroll
  for (int m = 0; m < 4; ++m)
#pragma unroll
    for (int n = 0; n < 4; ++n)
#pragma unroll
      for (int j = 0; j < 4; ++j) {
        float logit = acc[m][n][j] * LOGIT_SCALE;
        int grow = brow + wr + m * 16 + rlane * 4 + j;
        int gcol = bcol + wc + n * 16 + clane;
        if (grow == gcol) diag[grow] = logit;
        acc[m][n][j] = __expf(logit);
      }

  // Row sums: reduce over n-fragments then across the 16-lane column group.
#pragma unroll
  for (int m = 0; m < 4; ++m)
#pragma unroll
    for (int j = 0; j < 4; ++j) {
      float rs = acc[m][0][j] + acc[m][1][j] + acc[m][2][j] + acc[m][3][j];
      rs += __shfl_xor(rs, 1);
      rs += __shfl_xor(rs, 2);
      rs += __shfl_xor(rs, 4);
      rs += __shfl_xor(rs, 8);
      if (clane == 0) atomicAdd(&row_sum[brow + wr + m * 16 + rlane * 4 + j], rs);
    }

  // Col sums: reduce over m-fragments and regs, then across the 4 row groups.
#pragma unroll
  for (int n = 0; n < 4; ++n) {
    float cs = 0.f;
#pragma unroll
    for (int m = 0; m < 4; ++m)
#pragma unroll
      for (int j = 0; j < 4; ++j) cs += acc[m][n][j];
    cs += __shfl_xor(cs, 16);
    cs += __shfl_xor(cs, 32);
    if (rlane == 0) atomicAdd(&col_sum[bcol + wc + n * 16 + clane], cs);
  }
}

__global__ __launch_bounds__(256) void finalize_kernel(const float* __restrict__ rs,
                                                       const float* __restrict__ cs,
                                                       const float* __restrict__ dg,
                                                       float* __restrict__ out) {
  float s = 0.f;
  for (int i = threadIdx.x; i < B_DIM; i += 256)
    s += 0.5f * (logf(rs[i]) + logf(cs[i])) - dg[i];
#pragma unroll
  for (int m = 1; m < 64; m <<= 1) s += __shfl_xor(s, m);
  __shared__ float red[4];
  if ((threadIdx.x & 63) == 0) red[threadIdx.x >> 6] = s;
  __syncthreads();
  if (threadIdx.x == 0)
    out[0] = (red[0] + red[1] + red[2] + red[3]) * (1.0f / (float)B_DIM);
}

extern "C" void kernel_launch(void* const* d_in, const int* in_sizes, int n_in,
                              void* d_out, int out_size, void* d_ws, size_t ws_size,
                              hipStream_t stream) {
  const float* p = (const float*)d_in[0];
  const float* t = (const float*)d_in[1];
  float* out = (float*)d_out;

  char* ws = (char*)d_ws;
  const size_t embBytes = (size_t)B_DIM * D_DIM;  // 8 MB fp8
  uint8_t* Pn = (uint8_t*)ws;
  uint8_t* Tn = (uint8_t*)(ws + embBytes);
  float* row_sum = (float*)(ws + 2 * embBytes);
  float* col_sum = row_sum + B_DIM;
  float* diag = col_sum + B_DIM;

  hipMemsetAsync(row_sum, 0, 2 * (size_t)B_DIM * sizeof(float), stream);
  normalize_kernel<<<B_DIM / 4, 256, 0, stream>>>(p, Pn);
  normalize_kernel<<<B_DIM / 4, 256, 0, stream>>>(t, Tn);
  infonce_main<<<(B_DIM / 128) * (B_DIM / 128), 256, 0, stream>>>(Pn, Tn, row_sum, col_sum, diag);
  finalize_kernel<<<1, 256, 0, stream>>>(row_sum, col_sum, diag, out);
}